// Round 1
// baseline (306.845 us; speedup 1.0000x reference)
//
#include <hip/hip_runtime.h>

#define T_LEN 2048
#define GROUP 16
#define NG (T_LEN / GROUP)
#define KH 28.853901f /* 20 * log2(e): heaviside(x) = 1/(1+exp2(-KH*x)) */

// h(x) given negKx = -KH*x
__device__ __forceinline__ float hs_neg(float negKx) {
    float e = __builtin_amdgcn_exp2f(negKx);
    return __builtin_amdgcn_rcpf(1.0f + e);
}

#define PREFETCH(BUF, G) do {                                                  \
    const float4* s4_ = (const float4*)(row + (size_t)(G) * (3 * GROUP));      \
    _Pragma("unroll")                                                          \
    for (int j_ = 0; j_ < (3 * GROUP) / 4; ++j_) {                             \
        float4 v_ = s4_[j_];                                                   \
        BUF[4*j_+0] = v_.x; BUF[4*j_+1] = v_.y;                                \
        BUF[4*j_+2] = v_.z; BUF[4*j_+3] = v_.w;                                \
    } } while (0)

#define COMPUTE(BUF, G) do {                                                   \
    float qv[GROUP];                                                           \
    _Pragma("unroll")                                                          \
    for (int i_ = 0; i_ < GROUP; ++i_) {                                       \
        float pet = BUF[3*i_ + 0];                                             \
        float p   = BUF[3*i_ + 2];                                             \
        float Kpet = KH * pet;                                                 \
        /* et1 = soft-min(wu, pet); a = h(wu - pet) */                         \
        float a   = hs_neg(fmaf(-KH, wu, Kpet));                               \
        float et1 = fmaf(a, pet - wu, wu);                                     \
        /* rem = h(pet - et1) * (pet - et1) */                                 \
        float x   = pet - et1;                                                 \
        float hx  = hs_neg(fmaf(KH, et1, -Kpet));                              \
        float rem = hx * x;                                                    \
        /* et22 = soft-min(rem, wl); b2 = h(rem - wl) */                       \
        float b2   = hs_neg(fmaf(-KH, rem, KH * wl));                          \
        float et22 = fmaf(b2, wl - rem, rem);                                  \
        float hrem = hs_neg(-KH * rem);                                        \
        float et2  = hrem * et22;                                              \
        /* et33 = soft-min(u, wd); u = rem - et2 */                            \
        float u    = rem - et2;                                                \
        float c2   = hs_neg(fmaf(-KH, u, KH * wd));                            \
        float et33 = fmaf(c2, wd - u, u);                                      \
        float hu   = hs_neg(-KH * u);                                          \
        float et3  = hu * et33;                                                \
        /* state update (clip at +-1e5 is identity for these magnitudes) */    \
        float d1 = p - et1;  wu += d1;                                         \
        float d2 = d1 - et2; wl += d2;                                         \
        float d3 = d2 - et3; wd += d3;                                         \
        /* runoff_production(wu, wd, wl, ...): s uses wu and wd states */      \
        float ru = wu * inv_wt;                                                \
        float rd = wd * inv_wt;                                                \
        float s  = fmaf(c_s * ru, ru, b_s * rd * rd);                          \
        float ps = p - s;                                                      \
        float runoff = hs_neg(-KH * ps) * ps;                                  \
        qv[i_] = runoff * Kq;                                                  \
    }                                                                          \
    float4* d4_ = (float4*)(orow + (size_t)(G) * GROUP);                       \
    _Pragma("unroll")                                                          \
    for (int j_ = 0; j_ < GROUP / 4; ++j_) {                                   \
        d4_[j_] = make_float4(qv[4*j_], qv[4*j_+1], qv[4*j_+2], qv[4*j_+3]);   \
    } } while (0)

__global__ __launch_bounds__(64, 1)
void xaj_scan_kernel(const float* __restrict__ inp,
                     const float* __restrict__ p_wum,
                     const float* __restrict__ p_wlm,
                     const float* __restrict__ p_wdm,
                     const float* __restrict__ p_c,
                     const float* __restrict__ p_b,
                     const float* __restrict__ p_k1,
                     const float* __restrict__ p_k2,
                     const float* __restrict__ p_k3,
                     float* __restrict__ out)
{
    const int b = blockIdx.x * blockDim.x + threadIdx.x;
    const float* __restrict__ row  = inp + (size_t)b * (3 * T_LEN);
    float* __restrict__       orow = out + (size_t)b * T_LEN;

    const float wum = p_wum[0], wlm = p_wlm[0], wdm = p_wdm[0];
    const float cc  = p_c[0],   bb  = p_b[0];
    const float k1  = p_k1[0],  k2  = p_k2[0],  k3 = p_k3[0];

    // runoff_production is called as (wu, wd, wl, p, wum, wdm, wlm, b, c):
    //   wum_s = wum*19.9 + 0.1
    //   "wlm" param = wdm_true -> *30 + 60
    //   "wdm" param = wlm_true -> *60 + 60
    const float w_total = (wum * 19.9f + 0.1f)
                        + (wdm * 30.0f + 60.0f)
                        + (wlm * 60.0f + 60.0f);
    const float inv_wt = 1.0f / w_total;
    const float c_s = cc * 0.19f + 0.01f;
    const float b_s = bb * 0.3f  + 0.1f;
    const float k1s = k1 * 0.69f + 0.01f;
    const float k2s = k2 * 0.69f + 0.01f;
    const float k3s = k3 * 0.89f + 0.01f;
    // total_q = runoff * Kq  (water_source_partition + flow_routing folded)
    const float Kq = k1s + 0.5f * k2s * (1.0f - k1s)
                   + 0.25f * k3s * (1.0f - k1s) * (1.0f - k2s);

    float wu = 0.0f, wl = 0.0f, wd = 0.0f;

    float bufA[3 * GROUP];
    float bufB[3 * GROUP];

    PREFETCH(bufA, 0);

    for (int g = 0; g < NG; g += 2) {
        PREFETCH(bufB, g + 1);
        COMPUTE(bufA, g);
        if (g + 2 < NG) PREFETCH(bufA, g + 2);
        COMPUTE(bufB, g + 1);
    }
}

extern "C" void kernel_launch(void* const* d_in, const int* in_sizes, int n_in,
                              void* d_out, int out_size, void* d_ws, size_t ws_size,
                              hipStream_t stream) {
    const float* inp = (const float*)d_in[0];
    const int B = out_size / T_LEN;            // 4096
    dim3 block(64), grid((B + 63) / 64);
    xaj_scan_kernel<<<grid, block, 0, stream>>>(
        inp,
        (const float*)d_in[1],  // wum
        (const float*)d_in[2],  // wlm
        (const float*)d_in[3],  // wdm
        (const float*)d_in[4],  // c
        (const float*)d_in[5],  // b
        (const float*)d_in[6],  // k1
        (const float*)d_in[7],  // k2
        (const float*)d_in[8],  // k3
        (float*)d_out);
}

// Round 2
// 288.389 us; speedup vs baseline: 1.0640x; 1.0640x over previous
//
#include <hip/hip_runtime.h>

#define T_LEN 2048
#define GROUP 16
#define NG (T_LEN / GROUP)
#define KH 28.853901f /* 20 * log2(e): heaviside(x) = 1/(1+exp2(-KH*x)) */

// h(x) given negKx = -KH*x
__device__ __forceinline__ float hs_neg(float negKx) {
    float e = __builtin_amdgcn_exp2f(negKx);
    return __builtin_amdgcn_rcpf(1.0f + e);
}

// component access with compile-time-constant c (folds after unroll)
__device__ __forceinline__ float f4c(const float4& v, int c) {
    switch (c) { case 0: return v.x; case 1: return v.y; case 2: return v.z; default: return v.w; }
}

#define PREFETCH(BUF, G) do {                                                  \
    const float4* s4_ = (const float4*)(row + (size_t)(G) * (3 * GROUP));      \
    _Pragma("unroll")                                                          \
    for (int j_ = 0; j_ < 12; ++j_) { BUF[j_] = s4_[j_]; }                     \
    } while (0)

#define COMPUTE(BUF, G) do {                                                   \
    float qv[GROUP];                                                           \
    _Pragma("unroll")                                                          \
    for (int i_ = 0; i_ < GROUP; ++i_) {                                       \
        float pet = f4c(BUF[(3*i_ + 0) >> 2], (3*i_ + 0) & 3);                 \
        float p   = f4c(BUF[(3*i_ + 2) >> 2], (3*i_ + 2) & 3);                 \
        float Kpet = KH * pet;                                                 \
        /* et1 = soft-min(wu, pet); a = h(wu - pet) */                         \
        float a   = hs_neg(fmaf(-KH, wu, Kpet));                               \
        float et1 = fmaf(a, pet - wu, wu);                                     \
        /* rem = h(pet - et1) * (pet - et1) */                                 \
        float x   = pet - et1;                                                 \
        float hx  = hs_neg(fmaf(KH, et1, -Kpet));                              \
        float rem = hx * x;                                                    \
        /* et22 = soft-min(rem, wl); b2 = h(rem - wl) */                       \
        float b2   = hs_neg(fmaf(-KH, rem, KH * wl));                          \
        float et22 = fmaf(b2, wl - rem, rem);                                  \
        float hrem = hs_neg(-KH * rem);                                        \
        float et2  = hrem * et22;                                              \
        /* et33 = soft-min(u, wd); u = rem - et2 */                            \
        float u    = rem - et2;                                                \
        float c2   = hs_neg(fmaf(-KH, u, KH * wd));                            \
        float et33 = fmaf(c2, wd - u, u);                                      \
        float hu   = hs_neg(-KH * u);                                          \
        float et3  = hu * et33;                                                \
        /* state update (clip at +-1e5 is identity for these magnitudes) */    \
        float d1 = p - et1;  wu += d1;                                         \
        float d2 = d1 - et2; wl += d2;                                         \
        float d3 = d2 - et3; wd += d3;                                         \
        /* runoff_production(wu, wd, wl, ...): s uses wu and wd states */      \
        float ru = wu * inv_wt;                                                \
        float rd = wd * inv_wt;                                                \
        float s  = fmaf(c_s * ru, ru, b_s * rd * rd);                          \
        float ps = p - s;                                                      \
        float runoff = hs_neg(-KH * ps) * ps;                                  \
        qv[i_] = runoff * Kq;                                                  \
    }                                                                          \
    float4* d4_ = (float4*)(orow + (size_t)(G) * GROUP);                       \
    _Pragma("unroll")                                                          \
    for (int j_ = 0; j_ < GROUP / 4; ++j_) {                                   \
        d4_[j_] = make_float4(qv[4*j_], qv[4*j_+1], qv[4*j_+2], qv[4*j_+3]);   \
    } } while (0)

__global__ __launch_bounds__(64, 1)
void xaj_scan_kernel(const float* __restrict__ inp,
                     const float* __restrict__ p_wum,
                     const float* __restrict__ p_wlm,
                     const float* __restrict__ p_wdm,
                     const float* __restrict__ p_c,
                     const float* __restrict__ p_b,
                     const float* __restrict__ p_k1,
                     const float* __restrict__ p_k2,
                     const float* __restrict__ p_k3,
                     float* __restrict__ out)
{
    const int b = blockIdx.x * blockDim.x + threadIdx.x;
    const float* __restrict__ row  = inp + (size_t)b * (3 * T_LEN);
    float* __restrict__       orow = out + (size_t)b * T_LEN;

    const float wum = p_wum[0], wlm = p_wlm[0], wdm = p_wdm[0];
    const float cc  = p_c[0],   bb  = p_b[0];
    const float k1  = p_k1[0],  k2  = p_k2[0],  k3 = p_k3[0];

    // runoff_production is called as (wu, wd, wl, p, wum, wdm, wlm, b, c):
    //   wum_s = wum*19.9 + 0.1
    //   "wlm" param = wdm_true -> *30 + 60
    //   "wdm" param = wlm_true -> *60 + 60
    const float w_total = (wum * 19.9f + 0.1f)
                        + (wdm * 30.0f + 60.0f)
                        + (wlm * 60.0f + 60.0f);
    const float inv_wt = 1.0f / w_total;
    const float c_s = cc * 0.19f + 0.01f;
    const float b_s = bb * 0.3f  + 0.1f;
    const float k1s = k1 * 0.69f + 0.01f;
    const float k2s = k2 * 0.69f + 0.01f;
    const float k3s = k3 * 0.89f + 0.01f;
    // total_q = runoff * Kq  (water_source_partition + flow_routing folded)
    const float Kq = k1s + 0.5f * k2s * (1.0f - k1s)
                   + 0.25f * k3s * (1.0f - k1s) * (1.0f - k2s);

    float wu = 0.0f, wl = 0.0f, wd = 0.0f;

    float4 bufA[12];
    float4 bufB[12];

    PREFETCH(bufA, 0);
    __builtin_amdgcn_sched_barrier(0);

    for (int g = 0; g < NG; g += 2) {
        PREFETCH(bufB, g + 1);
        __builtin_amdgcn_sched_barrier(0);   // pin prefetch above compute
        COMPUTE(bufA, g);
        if (g + 2 < NG) PREFETCH(bufA, g + 2);
        __builtin_amdgcn_sched_barrier(0);   // pin prefetch above compute
        COMPUTE(bufB, g + 1);
    }
}

extern "C" void kernel_launch(void* const* d_in, const int* in_sizes, int n_in,
                              void* d_out, int out_size, void* d_ws, size_t ws_size,
                              hipStream_t stream) {
    const float* inp = (const float*)d_in[0];
    const int B = out_size / T_LEN;            // 4096
    dim3 block(64), grid((B + 63) / 64);
    xaj_scan_kernel<<<grid, block, 0, stream>>>(
        inp,
        (const float*)d_in[1],  // wum
        (const float*)d_in[2],  // wlm
        (const float*)d_in[3],  // wdm
        (const float*)d_in[4],  // c
        (const float*)d_in[5],  // b
        (const float*)d_in[6],  // k1
        (const float*)d_in[7],  // k2
        (const float*)d_in[8],  // k3
        (float*)d_out);
}

// Round 5
// 268.795 us; speedup vs baseline: 1.1416x; 1.0729x over previous
//
#include <hip/hip_runtime.h>

typedef float f32x4 __attribute__((ext_vector_type(4)));

#define T_LEN 2048
#define GROUP 32
#define NG (T_LEN / GROUP)    /* 64 groups */
#define CH 24                 /* 16B chunks per lane per group: 32*3*4/16 */
#define KH 28.853901f         /* 20*log2(e): heaviside(x) = 1/(1+exp2(-KH*x)) */

// h(x) given negKx = -KH*x
__device__ __forceinline__ float hs_neg(float negKx) {
    float e = __builtin_amdgcn_exp2f(negKx);
    return __builtin_amdgcn_rcpf(1.0f + e);
}

// Wait until at most N VMEM ops outstanding. Consumers of staged data are
// ds_reads (memory ops) -> properly ordered by the "memory" clobber; no
// reliance on compiler modeling of asm-load outputs (there are none).
#define WAITV(N) asm volatile("s_waitcnt vmcnt(" #N ")" ::: "memory")

// Async global->LDS: lane i's 16B land at LDSBASE + j*64 lanes + i (f32x4).
#define DMA_GROUP(LDSBASE, GPTR) do {                                          \
    const float* g_ = (GPTR);                                                  \
    f32x4* l_ = (LDSBASE);                                                     \
    _Pragma("unroll")                                                          \
    for (int j_ = 0; j_ < CH; ++j_) {                                          \
        __builtin_amdgcn_global_load_lds(                                      \
            (const __attribute__((address_space(1))) void*)(g_ + 4 * j_),      \
            (__attribute__((address_space(3))) void*)(l_ + (size_t)j_ * 64),   \
            16, 0, 0);                                                         \
    } } while (0)

#define LOAD_FV(CUR) do {                                                      \
    _Pragma("unroll")                                                          \
    for (int j_ = 0; j_ < CH; ++j_) fv[j_] = (CUR)[(size_t)j_ * 64 + lane];    \
    } while (0)

#define GB(K) (fv[(K) >> 2][(K) & 3])

// ---- 4-stage software-pipelined slot: S3(j-2) | S2(j-1) | S1(j) | OUT(j-2) ----
// Krem_p = -KH*rem, Ku_p = -KH*u. Order within slot: S3, S2, S1, OUT, shifts.
#define SLOT(J) do {                                                           \
    if ((J) >= 2) { /* S3: et3, wd for step J-2 */                             \
        float c2   = hs_neg(fmaf(KH, wd, Ku_p));   /* h(u - wd) */             \
        float hu   = hs_neg(Ku_p);                 /* h(u)      */             \
        float et33 = fmaf(c2, wd - u_p, u_p);                                  \
        float et3  = hu * et33;                                                \
        wd += d2_p - et3;                                                      \
    }                                                                          \
    if ((J) >= 1 && (J) <= GROUP) { /* S2: et2, wl for step J-1 */             \
        float b2   = hs_neg(fmaf(KH, wl, Krem_p)); /* h(rem - wl) */           \
        float hrem = hs_neg(Krem_p);               /* h(rem)      */           \
        float et22 = fmaf(b2, wl - rem_p, rem_p);                              \
        float et2  = hrem * et22;                                              \
        float u    = rem_p - et2;                                              \
        float d2   = d1_p - et2;                                               \
        wl += d2;                                                              \
        u_p = u; Ku_p = -KH * u; d2_p = d2;                                    \
    }                                                                          \
    if ((J) < GROUP) { /* S1: et1, wu, rem for step J */                       \
        float pet  = GB(3 * (J));                                              \
        float p    = GB(3 * (J) + 2);                                          \
        float Kpet = KH * pet;                                                 \
        float a    = hs_neg(fmaf(-KH, wu, Kpet));  /* h(wu - pet)  */          \
        float et1  = fmaf(a, pet - wu, wu);                                    \
        float x    = pet - et1;                                                \
        float hx   = hs_neg(fmaf(KH, et1, -Kpet)); /* h(pet - et1) */          \
        float rem  = hx * x;                                                   \
        float d1   = p - et1;                                                  \
        wu += d1;                                                              \
        rem_p = rem; Krem_p = -KH * rem; d1_p = d1;                            \
        p_new = p;                                                             \
    }                                                                          \
    if ((J) >= 2) { /* OUT for step J-2: wu(J-2), wd(J-2), p(J-2) */           \
        float ru = wu_s2 * inv_wt;                                             \
        float rd = wd * inv_wt;                                                \
        float s  = fmaf(c_s * ru, ru, (b_s * rd) * rd);                        \
        float ps = p_s2 - s;                                                   \
        float runoff = hs_neg(-KH * ps) * ps;                                  \
        qv[(J) - 2] = runoff * Kq;                                             \
    }                                                                          \
    wu_s2 = wu_s1; wu_s1 = wu;                                                 \
    p_s2  = p_s1;  p_s1  = p_new;                                              \
} while (0)

#define SLOTS_0_3()  do { SLOT(0); SLOT(1); SLOT(2); SLOT(3); } while (0)
#define SLOTS_4_33() do { \
    SLOT(4);  SLOT(5);  SLOT(6);  SLOT(7);  SLOT(8);  SLOT(9);  SLOT(10); \
    SLOT(11); SLOT(12); SLOT(13); SLOT(14); SLOT(15); SLOT(16); SLOT(17); \
    SLOT(18); SLOT(19); SLOT(20); SLOT(21); SLOT(22); SLOT(23); SLOT(24); \
    SLOT(25); SLOT(26); SLOT(27); SLOT(28); SLOT(29); SLOT(30); SLOT(31); \
    SLOT(32); SLOT(33); } while (0)

#define STOREQ() do {                                                          \
    f32x4* o4_ = (f32x4*)orow;                                                 \
    _Pragma("unroll")                                                          \
    for (int i_ = 0; i_ < GROUP / 4; ++i_) {                                   \
        f32x4 q_ = {qv[4*i_], qv[4*i_+1], qv[4*i_+2], qv[4*i_+3]};             \
        o4_[i_] = q_;                                                          \
    }                                                                          \
    orow += GROUP; } while (0)

__global__ __launch_bounds__(64, 1)
void xaj_scan_kernel(const float* __restrict__ inp,
                     const float* __restrict__ p_wum,
                     const float* __restrict__ p_wlm,
                     const float* __restrict__ p_wdm,
                     const float* __restrict__ p_c,
                     const float* __restrict__ p_b,
                     const float* __restrict__ p_k1,
                     const float* __restrict__ p_k2,
                     const float* __restrict__ p_k3,
                     float* __restrict__ out)
{
    __shared__ f32x4 sbuf[2][CH][64];   /* 48 KiB, double-buffered staging */

    const int lane = threadIdx.x;       /* block = 1 wave of 64 */
    const int b = blockIdx.x * 64 + lane;
    const float* __restrict__ row  = inp + (size_t)b * (3 * T_LEN);
    float*                    orow = out + (size_t)b * T_LEN;

    const float wum = p_wum[0], wlm = p_wlm[0], wdm = p_wdm[0];
    const float cc  = p_c[0],   bb  = p_b[0];
    const float k1  = p_k1[0],  k2  = p_k2[0],  k3 = p_k3[0];

    // runoff_production called as (wu, wd, wl, p, wum, wdm, wlm, b, c):
    // s = c_s*(wu/wt)^2 + b_s*(wd/wt)^2; wl never reaches the output.
    const float w_total = (wum * 19.9f + 0.1f)
                        + (wdm * 30.0f + 60.0f)
                        + (wlm * 60.0f + 60.0f);
    const float inv_wt = 1.0f / w_total;
    const float c_s = cc * 0.19f + 0.01f;
    const float b_s = bb * 0.3f  + 0.1f;
    const float k1s = k1 * 0.69f + 0.01f;
    const float k2s = k2 * 0.69f + 0.01f;
    const float k3s = k3 * 0.89f + 0.01f;
    const float Kq = k1s + 0.5f * k2s * (1.0f - k1s)
                   + 0.25f * k3s * (1.0f - k1s) * (1.0f - k2s);

    // scan states + pipeline registers
    float wu = 0.0f, wl = 0.0f, wd = 0.0f;
    float rem_p = 0.0f, Krem_p = 0.0f, d1_p = 0.0f;   // S1 -> S2
    float u_p = 0.0f, Ku_p = 0.0f, d2_p = 0.0f;       // S2 -> S3
    float wu_s1 = 0.0f, wu_s2 = 0.0f;                 // wu delayed 1,2 slots
    float p_s1 = 0.0f, p_s2 = 0.0f, p_new = 0.0f;     // p delayed 1,2 slots
    float qv[GROUP];
    f32x4 fv[CH];

    f32x4* cur = &sbuf[0][0][0];
    f32x4* nxt = &sbuf[1][0][0];

    DMA_GROUP(cur, row);                 // group 0
    DMA_GROUP(nxt, row + 96);            // group 1
    WAITV(24);                           // group 0 resident (keeps group 1 in flight)

    // Steady-state FIFO at iteration end: [DMA(k+2) x24, stores x8] -> vmcnt(32)
    // guarantees DMA(k+1) landed before iteration k+1 reads it.
#pragma clang loop unroll(disable)
    for (int k = 0; k < NG; ++k) {
        LOAD_FV(cur);                    // ds_read_b128 x24 (compiler-managed lgkmcnt)
        SLOTS_0_3();
        if (k + 2 < NG) DMA_GROUP(cur, row + (size_t)(k + 2) * 96);
        SLOTS_4_33();
        STOREQ();
        if (k < NG - 2) { WAITV(32); } else { WAITV(8); }
        f32x4* t = cur; cur = nxt; nxt = t;
    }
}

extern "C" void kernel_launch(void* const* d_in, const int* in_sizes, int n_in,
                              void* d_out, int out_size, void* d_ws, size_t ws_size,
                              hipStream_t stream) {
    const float* inp = (const float*)d_in[0];
    const int B = out_size / T_LEN;            // 4096
    dim3 block(64), grid((B + 63) / 64);
    xaj_scan_kernel<<<grid, block, 0, stream>>>(
        inp,
        (const float*)d_in[1],  // wum
        (const float*)d_in[2],  // wlm
        (const float*)d_in[3],  // wdm
        (const float*)d_in[4],  // c
        (const float*)d_in[5],  // b
        (const float*)d_in[6],  // k1
        (const float*)d_in[7],  // k2
        (const float*)d_in[8],  // k3
        (float*)d_out);
}

// Round 6
// 137.065 us; speedup vs baseline: 2.2387x; 1.9611x over previous
//
#include <hip/hip_runtime.h>

typedef float f32x4 __attribute__((ext_vector_type(4)));

#define T_LEN 2048
#define GROUP 16
#define NG    (T_LEN / GROUP)   /* 128 groups */
#define NT    (NG + 3)          /* 131 pipeline ticks */
#define CH    12                /* 16B chunks per lane per group: 16*3*4/16 */
#define KH    28.853901f        /* 20*log2(e): heaviside(x) = 1/(1+exp2(-KH*x)) */

__device__ __forceinline__ float hs_neg(float negKx) {
    float e = __builtin_amdgcn_exp2f(negKx);
    return __builtin_amdgcn_rcpf(1.0f + e);
}

#define WAITV(N) asm volatile("s_waitcnt vmcnt(" #N ")" ::: "memory")
/* raw barrier: do NOT use __syncthreads() (it drains vmcnt(0), killing the
   DMA prefetch). lgkmcnt(0) makes this wave's LDS writes visible first. */
#define TICK_BARRIER() do {                                   \
    asm volatile("s_waitcnt lgkmcnt(0)" ::: "memory");        \
    __builtin_amdgcn_s_barrier();                             \
    __builtin_amdgcn_sched_barrier(0); } while (0)

#define DMA_GROUP(SLOT, G) do {                                                \
    const float* g_ = row + (size_t)(G) * (3 * GROUP);                         \
    _Pragma("unroll")                                                          \
    for (int j_ = 0; j_ < CH; ++j_) {                                          \
        __builtin_amdgcn_global_load_lds(                                      \
            (const __attribute__((address_space(1))) void*)(g_ + 4 * j_),      \
            (__attribute__((address_space(3))) void*)&s_in[SLOT][j_][0],       \
            16, 0, 0);                                                         \
    } } while (0)

__global__ __launch_bounds__(256, 1)
void xaj_pipe_kernel(const float* __restrict__ inp,
                     const float* __restrict__ p_wum,
                     const float* __restrict__ p_wlm,
                     const float* __restrict__ p_wdm,
                     const float* __restrict__ p_c,
                     const float* __restrict__ p_b,
                     const float* __restrict__ p_k1,
                     const float* __restrict__ p_k2,
                     const float* __restrict__ p_k3,
                     float* __restrict__ out)
{
    /* LDS: input ring-6 (72 KB) + pipeline rings (56 KB) = 128 KB */
    __shared__ f32x4 s_in [6][CH][64];
    __shared__ float s_rem[2][GROUP][64];
    __shared__ float s_d1 [2][GROUP][64];
    __shared__ float s_wu [4][GROUP][64];
    __shared__ float s_u  [2][GROUP][64];
    __shared__ float s_d2 [2][GROUP][64];
    __shared__ float s_wd [2][GROUP][64];

    const int lane  = threadIdx.x & 63;
    const int wv    = threadIdx.x >> 6;
    const int chain = blockIdx.x * 64 + lane;
    const float* __restrict__ row = inp + (size_t)chain * (3 * T_LEN);
    float* __restrict__ orow      = out + (size_t)chain * T_LEN;

    const float wum = p_wum[0], wlm = p_wlm[0], wdm = p_wdm[0];
    const float cc  = p_c[0],   bb  = p_b[0];
    const float k1  = p_k1[0],  k2  = p_k2[0],  k3 = p_k3[0];

    /* runoff_production called as (wu, wd, wl, p, wum, wdm, wlm, b, c):
       s = c_s*(wu/wt)^2 + b_s*(wd/wt)^2; note the wl<->wd / wlm<->wdm swaps. */
    const float w_total = (wum * 19.9f + 0.1f)
                        + (wdm * 30.0f + 60.0f)
                        + (wlm * 60.0f + 60.0f);
    const float inv_wt = 1.0f / w_total;
    const float c_s = cc * 0.19f + 0.01f;
    const float b_s = bb * 0.3f  + 0.1f;
    const float k1s = k1 * 0.69f + 0.01f;
    const float k2s = k2 * 0.69f + 0.01f;
    const float k3s = k3 * 0.89f + 0.01f;
    const float Kq = k1s + 0.5f * k2s * (1.0f - k1s)
                   + 0.25f * k3s * (1.0f - k1s) * (1.0f - k2s);

    float st = 0.0f;   /* per-wave scan state: wu (wv0) / wl (wv1) / wd (wv2) */

    if (wv == 0) {
        DMA_GROUP(0, 0);
        DMA_GROUP(1, 1);
    }

    /* tick t: W0 does group t, W1 group t-1, W2 group t-2, W3 group t-3.
       vmcnt (W0 only): at tick start queue=[DMA(t),DMA(t+1)]; WAITV(12)
       retains DMA(t+1). s_in slot lifetime: DMA issue t-2 .. W3 read t+3;
       next write of same slot at t+4 (ring 6)  -> barrier-separated. */
    for (int t = 0; t < NT; ++t) {
        if (wv == 0) {
            if (t < NG) {
                if (t < NG - 1) { WAITV(12); } else { WAITV(0); }
                f32x4 fv[CH];
                const int s6 = t % 6;
#pragma unroll
                for (int j = 0; j < CH; ++j) fv[j] = s_in[s6][j][lane];
                if (t + 2 < NG) DMA_GROUP((t + 2) % 6, t + 2);
#pragma unroll
                for (int j = 0; j < GROUP; ++j) {
                    float pet = fv[(3*j)   >> 2][(3*j)   & 3];
                    float p   = fv[(3*j+2) >> 2][(3*j+2) & 3];
                    float dwp = pet - st;                        /* pet-wu */
                    float a   = hs_neg(KH * dwp);                /* h(wu-pet) */
                    float et1 = fmaf(a, dwp, st);
                    float x   = pet - et1;
                    float hx  = hs_neg(fmaf(KH, et1, -KH * pet)); /* h(pet-et1) */
                    float rem = hx * x;
                    float d1  = p - et1;
                    st = fmaf(-a, dwp, p);                       /* wu+p-et1 */
                    s_rem[t & 1][j][lane] = rem;
                    s_d1 [t & 1][j][lane] = d1;
                    s_wu [t & 3][j][lane] = st;
                }
            }
        } else if (wv == 1) {
            const int g = t - 1;
            if (g >= 0 && g < NG) {
#pragma unroll
                for (int j = 0; j < GROUP; ++j) {
                    float rem  = s_rem[g & 1][j][lane];
                    float d1   = s_d1 [g & 1][j][lane];
                    float nKr  = -KH * rem;
                    float b2   = hs_neg(fmaf(KH, st, nKr));  /* h(rem-wl) */
                    float hrem = hs_neg(nKr);                /* h(rem)    */
                    float et22 = fmaf(b2, st - rem, rem);
                    float et2  = hrem * et22;
                    float u    = rem - et2;
                    float d2   = d1 - et2;
                    float wld1 = st + d1;
                    st = fmaf(-hrem, et22, wld1);            /* wl+d1-et2 */
                    s_u [g & 1][j][lane] = u;
                    s_d2[g & 1][j][lane] = d2;
                }
            }
        } else if (wv == 2) {
            const int g = t - 2;
            if (g >= 0 && g < NG) {
#pragma unroll
                for (int j = 0; j < GROUP; ++j) {
                    float u    = s_u [g & 1][j][lane];
                    float d2   = s_d2[g & 1][j][lane];
                    float nKu  = -KH * u;
                    float c2   = hs_neg(fmaf(KH, st, nKu));  /* h(u-wd) */
                    float hu   = hs_neg(nKu);                /* h(u)    */
                    float et33 = fmaf(c2, st - u, u);
                    float wdd2 = st + d2;
                    st = fmaf(-hu, et33, wdd2);              /* wd+d2-et3 */
                    s_wd[g & 1][j][lane] = st;
                }
            }
        } else {
            const int g = t - 3;
            if (g >= 0) {   /* g <= NG-1 by loop bound */
                float qv[GROUP];
                const float* pin = (const float*)&s_in[g % 6][0][0];
#pragma unroll
                for (int j = 0; j < GROUP; ++j) {
                    float wuv = s_wu[g & 3][j][lane];
                    float wdv = s_wd[g & 1][j][lane];
                    const int f = 3 * j + 2;
                    float p  = pin[(f >> 2) * 256 + lane * 4 + (f & 3)];
                    float ru = wuv * inv_wt;
                    float rd = wdv * inv_wt;
                    float s2 = fmaf(c_s * ru, ru, (b_s * rd) * rd);
                    float ps = p - s2;
                    qv[j] = hs_neg(-KH * ps) * ps * Kq;
                }
                f32x4* o4 = (f32x4*)(orow + (size_t)g * GROUP);
#pragma unroll
                for (int i = 0; i < GROUP / 4; ++i) {
                    f32x4 q = {qv[4*i], qv[4*i+1], qv[4*i+2], qv[4*i+3]};
                    o4[i] = q;
                }
            }
        }
        TICK_BARRIER();
    }
}

extern "C" void kernel_launch(void* const* d_in, const int* in_sizes, int n_in,
                              void* d_out, int out_size, void* d_ws, size_t ws_size,
                              hipStream_t stream) {
    const float* inp = (const float*)d_in[0];
    const int B = out_size / T_LEN;            // 4096
    dim3 block(256), grid(B / 64);
    xaj_pipe_kernel<<<grid, block, 0, stream>>>(
        inp,
        (const float*)d_in[1],  // wum
        (const float*)d_in[2],  // wlm
        (const float*)d_in[3],  // wdm
        (const float*)d_in[4],  // c
        (const float*)d_in[5],  // b
        (const float*)d_in[6],  // k1
        (const float*)d_in[7],  // k2
        (const float*)d_in[8],  // k3
        (float*)d_out);
}